// Round 7
// baseline (566.008 us; speedup 1.0000x reference)
//
#include <hip/hip_runtime.h>
#include <stdint.h>

// Problem constants
#define NPIX   32768      // 32 * 32 * 32 flattened vectors
#define DIM    256        // embedding dim
#define KCODE  1024       // codebook entries
#define BSTRIDE 262144    // 256*32*32 floats per batch in NCHW
#define OUT0_N 8388608    // 32*256*32*32
// Exactness: |d_approx - d_chain| <= B ~ 8.7e-5 (round-4 analysis).
// THRESH > 2B; 3e-4 is hardware-proven in rounds 5-6 (absmax 0).
#define THRESH 3.0e-4f

typedef float f32x4 __attribute__((ext_vector_type(4)));
typedef short s16x8 __attribute__((ext_vector_type(8)));

__device__ __forceinline__ unsigned short bf16_rne(float x) {
    unsigned u = __float_as_uint(x);
    unsigned r = (u + 0x7fffu + ((u >> 16) & 1u)) >> 16;
    return (unsigned short)r;
}
__device__ __forceinline__ float bf16_to_f(unsigned short h) {
    return __uint_as_float(((unsigned)h) << 16);
}
// monotone float -> uint32 key (total order preserved for finite floats)
__device__ __forceinline__ unsigned int f2key(float f) {
    unsigned int u = __float_as_uint(f);
    return (u & 0x80000000u) ? ~u : (u | 0x80000000u);
}

// ---------------------------------------------------------------------------
// numpy pw128 accumulator chain piece (proven rounds 2-6).
// ---------------------------------------------------------------------------
__device__ __forceinline__ float sqchain(const float* __restrict__ base, int stride, int c0) {
    float v = base[(size_t)c0 * stride];
    float r = __fmul_rn(v, v);
#pragma unroll
    for (int i = 1; i < 16; ++i) {
        float u = base[(size_t)(c0 + 8 * i) * stride];
        r = __fadd_rn(r, __fmul_rn(u, u));
    }
    return r;
}

// ---------------------------------------------------------------------------
// Kernel 1: exact numpy-pairwise sums of squares (proven). Inits loss acc.
// ---------------------------------------------------------------------------
__global__ void vq_sums(const float* __restrict__ in, const float* __restrict__ emb,
                        float* __restrict__ sx_arr, float* __restrict__ se_arr,
                        float* __restrict__ loss_acc) {
    const int tid  = threadIdx.x;
    const int wave = tid >> 6;
    const int lane = tid & 63;
    const int jg   = lane >> 4;
    const int p    = lane & 15;
    const int n    = blockIdx.x * 64 + wave * 16 + p;
    if (blockIdx.x == 0 && tid == 0) *loss_acc = 0.0f;

    const float* base;
    int stride;
    if (n < NPIX) {
        base = in + (size_t)(n >> 10) * BSTRIDE + (n & 1023);
        stride = 1024;
    } else {
        base = emb + (size_t)(n - NPIX) * DIM;
        stride = 1;
    }
    const int c0 = 2 * jg;
    float glo = __fadd_rn(sqchain(base, stride, c0),       sqchain(base, stride, c0 + 1));
    float ghi = __fadd_rn(sqchain(base, stride, 128 + c0), sqchain(base, stride, 128 + c0 + 1));
    glo = __fadd_rn(glo, __shfl_xor(glo, 16, 64));
    glo = __fadd_rn(glo, __shfl_xor(glo, 32, 64));
    ghi = __fadd_rn(ghi, __shfl_xor(ghi, 16, 64));
    ghi = __fadd_rn(ghi, __shfl_xor(ghi, 32, 64));
    float s = __fadd_rn(glo, ghi);

    if (jg == 0) {
        if (n < NPIX) sx_arr[n] = s;
        else          se_arr[n - NPIX] = s;
    }
}

// ---------------------------------------------------------------------------
// Kernel 1b: codebook -> bf16 hi/lo planes ([k][d]) + exact fp32 transpose
// embT[d][k] (for the coalesced slow path); zero queue ctr.
// ---------------------------------------------------------------------------
__global__ void vq_prep(const float* __restrict__ emb,
                        unsigned short* __restrict__ eh, unsigned short* __restrict__ el,
                        float* __restrict__ embT,
                        int* __restrict__ qcount) {
    const int gid = blockIdx.x * 256 + threadIdx.x;   // 65536 threads
    if (gid == 0) *qcount = 0;
#pragma unroll
    for (int i = 0; i < 4; ++i) {
        int idx = gid + 65536 * i;                    // idx = k*256 + d
        float v = emb[idx];
        unsigned short h = bf16_rne(v);
        float l = v - bf16_to_f(h);
        eh[idx] = h;
        el[idx] = bf16_rne(l);
        embT[(size_t)(idx & 255) * KCODE + (idx >> 8)] = v;   // exact fp32 copy
    }
}

// ---------------------------------------------------------------------------
// Kernel 2: MFMA approximate-distance argmin with exact top-2 tracking.
// Round-7 change: REGISTER-PREFETCH PIPELINE for the es staging. Round 6's
// structure issued the global es loads between the two barriers of the SAME
// ds-iteration -> 64 serialized ~500-cyc L2 round trips per block (~200 us
// kernel). Now slice (cc,ds+1) is prefetched into regs right after slice
// (cc,ds) is written to LDS, so the load latency overlaps the MFMA section
// and the next barrier. +32 VGPR is safe: LDS-bound at 2 blocks/CU ->
// 2 waves/SIMD -> 256-VGPR budget (no launch_bounds reg cap — r2 lesson).
// Everything else (layout, gating, numerics) proven rounds 5-6.
// ---------------------------------------------------------------------------
__global__ __launch_bounds__(256, 2)
void vq_mfma(const float* __restrict__ in,
             const unsigned short* __restrict__ ebf_h, const unsigned short* __restrict__ ebf_l,
             const float* __restrict__ sx_arr, const float* __restrict__ se_arr,
             unsigned long long* __restrict__ ws64,
             int* __restrict__ qcount, int* __restrict__ qlist) {
    const int n0  = blockIdx.x << 5;       // 32 pixels per block
    const int b   = n0 >> 10;
    const int hw0 = n0 & 1023;
    const int tid = threadIdx.x;
    const int w    = tid >> 6;
    const int lane = tid & 63;
    const int quad = lane >> 4;
    const int l15  = lane & 15;

    __shared__ unsigned short xh[32][264];
    __shared__ unsigned short xl[32][264];
    __shared__ unsigned short es_h[256][40];
    __shared__ unsigned short es_l[256][40];
    __shared__ float red[4][32][4];

    // ---- stage x tile (32 px x 256 d), split fp32 -> bf16 hi/lo ----
    {
        const int px = tid & 31;
        const int dbase = (tid >> 5) * 32;
        const float* xp = in + (size_t)b * BSTRIDE + hw0 + px;
#pragma unroll 8
        for (int dd = 0; dd < 32; ++dd) {
            const int d = dbase + dd;
            float v = xp[(size_t)d * 1024];
            unsigned short hb = bf16_rne(v);
            float l = v - bf16_to_f(hb);
            xh[px][d] = hb;
            xl[px][d] = bf16_rne(l);
        }
    }

    // sx for this lane's 8 pixel-slots: px = 16*m + quad*4 + r
    float sxv[2][4];
#pragma unroll
    for (int m = 0; m < 2; ++m) {
        float4 t = *(const float4*)(sx_arr + n0 + 16 * m + quad * 4);
        sxv[m][0] = t.x; sxv[m][1] = t.y; sxv[m][2] = t.z; sxv[m][3] = t.w;
    }

    float t1[8], t2[8];
    int   k1[8], k2[8];
#pragma unroll
    for (int i = 0; i < 8; ++i) {
        t1[i] = __uint_as_float(0x7f800000u); t2[i] = t1[i];
        k1[i] = 0; k2[i] = 0;
    }

    // es-slice prefetch registers (thread stages 64 B per plane per slice)
    uint4 ph[4], pl[4];
    {
        const unsigned short* gh = ebf_h + (size_t)tid * DIM;   // cc=0, ds=0
        const unsigned short* gl = ebf_l + (size_t)tid * DIM;
#pragma unroll
        for (int q = 0; q < 4; ++q) {
            ph[q] = *(const uint4*)(gh + q * 8);
            pl[q] = *(const uint4*)(gl + q * 8);
        }
    }

    for (int cc = 0; cc < 4; ++cc) {
        const int kc = cc << 8;
        f32x4 acc[2][4];
#pragma unroll
        for (int m = 0; m < 2; ++m)
#pragma unroll
            for (int ns = 0; ns < 4; ++ns)
                acc[m][ns] = (f32x4){0.f, 0.f, 0.f, 0.f};

        for (int ds = 0; ds < 8; ++ds) {
            __syncthreads();   // prev-iteration frag readers done (also covers x-stage)
            // write current slice from prefetch regs
#pragma unroll
            for (int q = 0; q < 4; ++q) {
                *(uint4*)&es_h[tid][q * 8] = ph[q];
                *(uint4*)&es_l[tid][q * 8] = pl[q];
            }
            // prefetch next slice (overlaps barrier + MFMA below)
            {
                const int nxt = cc * 8 + ds + 1;
                if (nxt < 32) {
                    const int kcn = (nxt >> 3) << 8;
                    const int dsn = nxt & 7;
                    const unsigned short* gh = ebf_h + (size_t)(kcn + tid) * DIM + dsn * 32;
                    const unsigned short* gl = ebf_l + (size_t)(kcn + tid) * DIM + dsn * 32;
#pragma unroll
                    for (int q = 0; q < 4; ++q) {
                        ph[q] = *(const uint4*)(gh + q * 8);
                        pl[q] = *(const uint4*)(gl + q * 8);
                    }
                }
            }
            __syncthreads();
            // A-frags for both pixel-subtiles
            s16x8 a_h[2], a_l[2];
#pragma unroll
            for (int m = 0; m < 2; ++m) {
                a_h[m] = *(const s16x8*)&xh[16 * m + l15][ds * 32 + quad * 8];
                a_l[m] = *(const s16x8*)&xl[16 * m + l15][ds * 32 + quad * 8];
            }
#pragma unroll
            for (int ns = 0; ns < 4; ++ns) {
                const int cl = w * 64 + ns * 16 + l15;
                s16x8 bh = *(const s16x8*)&es_h[cl][quad * 8];
                s16x8 bl = *(const s16x8*)&es_l[cl][quad * 8];
#pragma unroll
                for (int m = 0; m < 2; ++m) {
                    acc[m][ns] = __builtin_amdgcn_mfma_f32_16x16x32_bf16(a_h[m], bh, acc[m][ns], 0, 0, 0);
                    acc[m][ns] = __builtin_amdgcn_mfma_f32_16x16x32_bf16(a_h[m], bl, acc[m][ns], 0, 0, 0);
                    acc[m][ns] = __builtin_amdgcn_mfma_f32_16x16x32_bf16(a_l[m], bh, acc[m][ns], 0, 0, 0);
                }
            }
        }
        // fold chunk into per-lane top-2 (k strictly ascending within lane)
#pragma unroll
        for (int ns = 0; ns < 4; ++ns) {
            const int c = kc + w * 64 + ns * 16 + l15;
            const float se = se_arr[c];
#pragma unroll
            for (int m = 0; m < 2; ++m) {
#pragma unroll
                for (int r = 0; r < 4; ++r) {
                    const int i = m * 4 + r;
                    float dv = __fadd_rn(__fmaf_rn(-2.0f, acc[m][ns][r], sxv[m][r]), se);
                    if (dv < t1[i]) { t2[i] = t1[i]; k2[i] = k1[i]; t1[i] = dv; k1[i] = c; }
                    else if (dv < t2[i]) { t2[i] = dv; k2[i] = c; }
                }
            }
        }
    }

    // width-16 butterfly merge of top-2 across the code dimension (l15)
#pragma unroll
    for (int mm = 1; mm < 16; mm <<= 1) {
#pragma unroll
        for (int i = 0; i < 8; ++i) {
            float ov1 = __shfl_xor(t1[i], mm, 16); int ok1 = __shfl_xor(k1[i], mm, 16);
            float ov2 = __shfl_xor(t2[i], mm, 16); int ok2 = __shfl_xor(k2[i], mm, 16);
            if (ov1 < t1[i] || (ov1 == t1[i] && ok1 < k1[i])) {
                t2[i] = t1[i]; k2[i] = k1[i]; t1[i] = ov1; k1[i] = ok1;
            } else if (ov1 < t2[i] || (ov1 == t2[i] && ok1 < k2[i])) {
                t2[i] = ov1; k2[i] = ok1;
            }
            if (ov2 < t2[i] || (ov2 == t2[i] && ok2 < k2[i])) {
                if (ov2 < t1[i] || (ov2 == t1[i] && ok2 < k1[i])) {
                    t2[i] = t1[i]; k2[i] = k1[i]; t1[i] = ov2; k1[i] = ok2;
                } else { t2[i] = ov2; k2[i] = ok2; }
            }
        }
    }
    // lane leaders publish per-wave top-2 per pixel
    if (l15 == 0) {
#pragma unroll
        for (int i = 0; i < 8; ++i) {
            const int px = 16 * (i >> 2) + quad * 4 + (i & 3);
            red[w][px][0] = t1[i];
            red[w][px][1] = __int_as_float(k1[i]);
            red[w][px][2] = t2[i];
            red[w][px][3] = __int_as_float(k2[i]);
        }
    }
    __syncthreads();
    if (tid < 32) {
        const int px = tid;
        float D1 = __uint_as_float(0x7f800000u), D2 = D1;
        int   K1 = 0, K2 = 0;
#pragma unroll
        for (int wv = 0; wv < 4; ++wv) {
            float a1 = red[wv][px][0]; int b1 = __float_as_int(red[wv][px][1]);
            float a2 = red[wv][px][2]; int b2 = __float_as_int(red[wv][px][3]);
            if (a1 < D1 || (a1 == D1 && b1 < K1)) { D2 = D1; K2 = K1; D1 = a1; K1 = b1; }
            else if (a1 < D2 || (a1 == D2 && b1 < K2)) { D2 = a1; K2 = b1; }
            if (a2 < D2 || (a2 == D2 && b2 < K2)) {
                if (a2 < D1 || (a2 == D1 && b2 < K1)) { D2 = D1; K2 = K1; D1 = a2; K1 = b2; }
                else { D2 = a2; K2 = b2; }
            }
        }
        ws64[n0 + px] = ((unsigned long long)f2key(D1) << 32) | (unsigned)K1;
        if (__fsub_rn(D2, D1) <= THRESH) {
            int qi = atomicAdd(qcount, 1);
            qlist[qi] = n0 + px;
        }
    }
}

// ---------------------------------------------------------------------------
// Kernel 2b: exact slow path, COALESCED via embT[d][k].
// Block = 4 queued pixels (one per wave). Lane l owns codes {4l+c+256g},
// c=0..3, g=0..3 (16 chains). Per d: x broadcast from LDS; 4 float4 loads
// embT[d][4l+256g] -> lane-consecutive addresses = fully coalesced 1 KB/instr
// (round 6's layout put lanes 32 KB apart -> 32 scattered lines/instr, the
// 237-us latency bind). Per-(n,k) fmac chain BIT-IDENTICAL to rounds 1-6
// (d ascending sequential); k visit order ascending (g outer, c inner) with
// strict < -> first-occurrence ties. Full-wave butterfly merge; plain store.
// ---------------------------------------------------------------------------
__global__ __launch_bounds__(256, 4)
void vq_slow(const float* __restrict__ in, const float* __restrict__ embT,
             const float* __restrict__ sx_arr, const float* __restrict__ se_arr,
             const int* __restrict__ qcount, const int* __restrict__ qlist,
             unsigned long long* __restrict__ ws64) {
    __shared__ float xs[4][256];
    const int nq = *qcount;
    const int t = threadIdx.x;
    const int w = t >> 6;    // pixel slot 0..3 (one wave per pixel)
    const int l = t & 63;

    for (int base = blockIdx.x * 4; base < nq; base += 1024 * 4) {
        const int qi = base + w;
        const bool valid = (qi < nq);
        const int n = qlist[valid ? qi : base];
        __syncthreads();   // previous-iteration readers done
        {
            const float* src = in + (size_t)(n >> 10) * BSTRIDE + (n & 1023);
#pragma unroll
            for (int i = 0; i < 4; ++i)
                xs[w][l + 64 * i] = src[(size_t)(l + 64 * i) * 1024];
        }
        __syncthreads();

        const float sx = sx_arr[n];
        float m[16];
#pragma unroll
        for (int j = 0; j < 16; ++j) m[j] = 0.0f;

#pragma unroll 2
        for (int d = 0; d < 256; ++d) {
            const float xv = xs[w][d];
            const float* row = embT + (size_t)d * KCODE + 4 * l;
#pragma unroll
            for (int g = 0; g < 4; ++g) {
                float4 ev = *(const float4*)(row + 256 * g);
                m[4 * g + 0] = __fmaf_rn(xv, ev.x, m[4 * g + 0]);
                m[4 * g + 1] = __fmaf_rn(xv, ev.y, m[4 * g + 1]);
                m[4 * g + 2] = __fmaf_rn(xv, ev.z, m[4 * g + 2]);
                m[4 * g + 3] = __fmaf_rn(xv, ev.w, m[4 * g + 3]);
            }
        }
        float bestv = __uint_as_float(0x7f800000u);
        int   bestk = 0;
#pragma unroll
        for (int g = 0; g < 4; ++g) {
#pragma unroll
            for (int c = 0; c < 4; ++c) {
                const int k = 4 * l + c + 256 * g;
                float dv = __fadd_rn(__fmaf_rn(-2.0f, m[4 * g + c], sx), se_arr[k]);
                if (dv < bestv) { bestv = dv; bestk = k; }   // k ascending, strict <
            }
        }
        // full-wave merge (64 lanes, one pixel per wave), tie -> smaller k
#pragma unroll
        for (int mm = 1; mm < 64; mm <<= 1) {
            float ov = __shfl_xor(bestv, mm, 64);
            int   ok = __shfl_xor(bestk, mm, 64);
            if (ov < bestv || (ov == bestv && ok < bestk)) { bestv = ov; bestk = ok; }
        }
        if (l == 0 && valid)
            ws64[n] = ((unsigned long long)f2key(bestv) << 32) | (unsigned)bestk;
    }
}

// ---------------------------------------------------------------------------
// Kernel 3: gather quantized rows, straight-through output + indices + loss.
// (unchanged, proven)
// ---------------------------------------------------------------------------
__global__ void vq_write(const float* __restrict__ in, const float* __restrict__ emb,
                         const unsigned long long* __restrict__ ws64,
                         float* __restrict__ out0, float* __restrict__ out2,
                         float* __restrict__ loss_acc) {
    const int nt = blockIdx.x;
    const int n0 = nt << 7;
    const int b  = n0 >> 10;
    const int hw0 = n0 & 1023;
    const int tid = threadIdx.x;
    const int n_l = tid & 127;
    const int ch0 = tid >> 7;

    const int k = (int)(unsigned int)(ws64[n0 + n_l] & 0xFFFFFFFFull);
    if (tid < 128) out2[n0 + tid] = (float)k;

    const float* xrow = in  + (size_t)b * BSTRIDE + hw0 + n_l;
    float*       orow = out0 + (size_t)b * BSTRIDE + hw0 + n_l;
    const float* erow = emb + (size_t)k * DIM;

    float lsum = 0.0f;
    for (int it = 0; it < 128; ++it) {
        const int ch = it * 2 + ch0;
        float x = xrow[(size_t)ch * 1024];
        float q = erow[ch];
        float df = __fsub_rn(q, x);
        orow[(size_t)ch * 1024] = __fadd_rn(x, df);
        lsum = __fadd_rn(lsum, __fmul_rn(df, df));
    }
#pragma unroll
    for (int off = 32; off >= 1; off >>= 1)
        lsum += __shfl_down(lsum, off, 64);
    __shared__ float wsum[4];
    if ((tid & 63) == 0) wsum[tid >> 6] = lsum;
    __syncthreads();
    if (tid == 0) {
        float tt = wsum[0] + wsum[1] + wsum[2] + wsum[3];
        atomicAdd(loss_acc, tt);
    }
}

// ---------------------------------------------------------------------------
// Kernel 4: finalize loss (unchanged).
// ---------------------------------------------------------------------------
__global__ void vq_loss(const float* __restrict__ loss_acc, float* __restrict__ out1) {
    float s = *loss_acc;
    float e = s * (1.0f / 8388608.0f);
    out1[0] = __fadd_rn(e, __fmul_rn(0.25f, e));
}

extern "C" void kernel_launch(void* const* d_in, const int* in_sizes, int n_in,
                              void* d_out, int out_size, void* d_ws, size_t ws_size,
                              hipStream_t stream) {
    const float* in  = (const float*)d_in[0];
    const float* emb = (const float*)d_in[1];
    float* out = (float*)d_out;

    // d_ws: proven layout
    unsigned long long* ws64 = (unsigned long long*)d_ws;          // 32768 * 8 B
    float* wsf     = (float*)((char*)d_ws + NPIX * sizeof(unsigned long long));
    float* lossacc = wsf;
    float* sx_arr  = wsf + 256;
    float* se_arr  = wsf + 256 + NPIX;

    // Scratch in d_out's quantized region (vq_write overwrites it all, last):
    // [0, 1 MB): ebf hi/lo planes; [1 MB, ~1.13 MB): qcount + qlist;
    // [2 MB, 3 MB): embT (fp32 transposed codebook).
    unsigned short* ebf_h = (unsigned short*)d_out;                // 262144 u16
    unsigned short* ebf_l = ebf_h + KCODE * DIM;                   // 262144 u16
    int* qcount = (int*)((char*)d_out + 2u * KCODE * DIM * sizeof(unsigned short));
    int* qlist  = qcount + 1;                                      // up to 32768 ints
    float* embT = (float*)((char*)d_out + (2u << 20));             // 262144 f32

    vq_sums<<<(NPIX + KCODE) / 64, 256, 0, stream>>>(in, emb, sx_arr, se_arr, lossacc);
    vq_prep<<<256, 256, 0, stream>>>(emb, ebf_h, ebf_l, embT, qcount);
    vq_mfma<<<1024, 256, 0, stream>>>(in, ebf_h, ebf_l, sx_arr, se_arr, ws64, qcount, qlist);
    vq_slow<<<1024, 256, 0, stream>>>(in, embT, sx_arr, se_arr, qcount, qlist, ws64);
    vq_write<<<256, 256, 0, stream>>>(in, emb, ws64, out, out + OUT0_N + 1, lossacc);
    vq_loss<<<1, 1, 0, stream>>>(lossacc, out + OUT0_N);
}

// Round 8
// 390.498 us; speedup vs baseline: 1.4495x; 1.4495x over previous
//
#include <hip/hip_runtime.h>
#include <stdint.h>

// Problem constants
#define NPIX   32768      // 32 * 32 * 32 flattened vectors
#define DIM    256        // embedding dim
#define KCODE  1024       // codebook entries
#define BSTRIDE 262144    // 256*32*32 floats per batch in NCHW
#define OUT0_N 8388608    // 32*256*32*32
// Exactness: |d_approx - d_chain| <= B ~ 8.7e-5 (round-4 analysis).
// THRESH > 2B; 3e-4 is hardware-proven in rounds 5-7 (absmax 0).
#define THRESH 3.0e-4f

typedef float f32x4 __attribute__((ext_vector_type(4)));
typedef short s16x8 __attribute__((ext_vector_type(8)));

__device__ __forceinline__ unsigned short bf16_rne(float x) {
    unsigned u = __float_as_uint(x);
    unsigned r = (u + 0x7fffu + ((u >> 16) & 1u)) >> 16;
    return (unsigned short)r;
}
__device__ __forceinline__ float bf16_to_f(unsigned short h) {
    return __uint_as_float(((unsigned)h) << 16);
}
// monotone float -> uint32 key (total order preserved for finite floats)
__device__ __forceinline__ unsigned int f2key(float f) {
    unsigned int u = __float_as_uint(f);
    return (u & 0x80000000u) ? ~u : (u | 0x80000000u);
}

// async global->LDS DMA, 16 B per lane. LDS dest MUST be wave-uniform base +
// lane*16 (m104/m108); global side is a per-lane gather (any addresses).
__device__ __forceinline__ void async_cp16(const unsigned short* g, unsigned short* l) {
    __builtin_amdgcn_global_load_lds(
        (const __attribute__((address_space(1))) void*)g,
        (__attribute__((address_space(3))) void*)l, 16, 0, 0);
}

// ---------------------------------------------------------------------------
// numpy pw128 accumulator chain piece (proven rounds 2-7).
// ---------------------------------------------------------------------------
__device__ __forceinline__ float sqchain(const float* __restrict__ base, int stride, int c0) {
    float v = base[(size_t)c0 * stride];
    float r = __fmul_rn(v, v);
#pragma unroll
    for (int i = 1; i < 16; ++i) {
        float u = base[(size_t)(c0 + 8 * i) * stride];
        r = __fadd_rn(r, __fmul_rn(u, u));
    }
    return r;
}

// ---------------------------------------------------------------------------
// Kernel 1: exact numpy-pairwise sums of squares (proven). Inits loss acc.
// ---------------------------------------------------------------------------
__global__ void vq_sums(const float* __restrict__ in, const float* __restrict__ emb,
                        float* __restrict__ sx_arr, float* __restrict__ se_arr,
                        float* __restrict__ loss_acc) {
    const int tid  = threadIdx.x;
    const int wave = tid >> 6;
    const int lane = tid & 63;
    const int jg   = lane >> 4;
    const int p    = lane & 15;
    const int n    = blockIdx.x * 64 + wave * 16 + p;
    if (blockIdx.x == 0 && tid == 0) *loss_acc = 0.0f;

    const float* base;
    int stride;
    if (n < NPIX) {
        base = in + (size_t)(n >> 10) * BSTRIDE + (n & 1023);
        stride = 1024;
    } else {
        base = emb + (size_t)(n - NPIX) * DIM;
        stride = 1;
    }
    const int c0 = 2 * jg;
    float glo = __fadd_rn(sqchain(base, stride, c0),       sqchain(base, stride, c0 + 1));
    float ghi = __fadd_rn(sqchain(base, stride, 128 + c0), sqchain(base, stride, 128 + c0 + 1));
    glo = __fadd_rn(glo, __shfl_xor(glo, 16, 64));
    glo = __fadd_rn(glo, __shfl_xor(glo, 32, 64));
    ghi = __fadd_rn(ghi, __shfl_xor(ghi, 16, 64));
    ghi = __fadd_rn(ghi, __shfl_xor(ghi, 32, 64));
    float s = __fadd_rn(glo, ghi);

    if (jg == 0) {
        if (n < NPIX) sx_arr[n] = s;
        else          se_arr[n - NPIX] = s;
    }
}

// ---------------------------------------------------------------------------
// Kernel 1b: codebook -> bf16 hi/lo planes ([k][d]) + exact fp32 transpose
// embT[d][k] (for the coalesced slow path); zero queue ctr.
// ---------------------------------------------------------------------------
__global__ void vq_prep(const float* __restrict__ emb,
                        unsigned short* __restrict__ eh, unsigned short* __restrict__ el,
                        float* __restrict__ embT,
                        int* __restrict__ qcount) {
    const int gid = blockIdx.x * 256 + threadIdx.x;   // 65536 threads
    if (gid == 0) *qcount = 0;
#pragma unroll
    for (int i = 0; i < 4; ++i) {
        int idx = gid + 65536 * i;                    // idx = k*256 + d
        float v = emb[idx];
        unsigned short h = bf16_rne(v);
        float l = v - bf16_to_f(h);
        eh[idx] = h;
        el[idx] = bf16_rne(l);
        embT[(size_t)(idx & 255) * KCODE + (idx >> 8)] = v;   // exact fp32 copy
    }
}

// ---------------------------------------------------------------------------
// Kernel 2: MFMA approx-distance argmin, exact top-2 gating (numerics and
// gating proven rounds 5-7; K-loop restructured this round).
//
// K-loop v3: async DMA double-buffer, ONE barrier per iteration.
//   iter idx (cc = idx>>3 -> 128-code chunk, ds = idx&7 -> 32-d slice):
//     issue global_load_lds of slice idx+1 into es[buf^1]   (DMA, no VGPRs)
//     MFMA-consume es[buf]; fold at ds==7
//     __syncthreads()  (drains DMA + LDS reads), buf ^= 1
//   Old shape was [barrier][glb->VGPR->LDS][barrier][MFMA]: a serialized
//   ~500-cyc L2 round trip per slice (~220 us). Register prefetch (r7)
//   spilled: 32 regs live across barriers -> 189 MB scratch. DMA holds the
//   in-flight data in neither VGPRs nor a stalled wave.
// es layout [buf][plane][q][code 128][8 u16]: thread t stages plane t>>7,
// code t&127, 4x16 B -> per-wave lane-contiguous LDS (DMA constraint ok);
// B-frag ds_read_b128 at code*16 B -> 2-way banks (free).
// LDS 33.8 (x) + 32 (es) + 2 (red) = 68.6 KB -> 2 blocks/CU.
// ---------------------------------------------------------------------------
__global__ __launch_bounds__(256, 2)
void vq_mfma(const float* __restrict__ in,
             const unsigned short* __restrict__ ebf_h, const unsigned short* __restrict__ ebf_l,
             const float* __restrict__ sx_arr, const float* __restrict__ se_arr,
             unsigned long long* __restrict__ ws64,
             int* __restrict__ qcount, int* __restrict__ qlist) {
    const int n0  = blockIdx.x << 5;       // 32 pixels per block
    const int b   = n0 >> 10;
    const int hw0 = n0 & 1023;
    const int tid = threadIdx.x;
    const int w    = tid >> 6;
    const int lane = tid & 63;
    const int quad = lane >> 4;
    const int l15  = lane & 15;

    __shared__ unsigned short xh[32][264];
    __shared__ unsigned short xl[32][264];
    __shared__ unsigned short es[2][2][4][128][8];
    __shared__ float red[4][32][4];

    // staging role for the es DMA
    const int scode  = tid & 127;
    const int splane = tid >> 7;
    const unsigned short* gplane = splane ? ebf_l : ebf_h;

    auto issue_es = [&](int idx, int bsel) {
        const int kc = (idx >> 3) << 7;
        const int ds = idx & 7;
        const unsigned short* g = gplane + (size_t)(kc + scode) * DIM + ds * 32;
        unsigned short* l0 = &es[bsel][splane][0][scode][0];
#pragma unroll
        for (int q = 0; q < 4; ++q)
            async_cp16(g + q * 8, l0 + q * 1024);   // q-stride = 128*8 u16
    };

    // kick off slice 0 while the VALU does the x-stage
    issue_es(0, 0);

    // ---- stage x tile (32 px x 256 d), split fp32 -> bf16 hi/lo ----
    {
        const int px = tid & 31;
        const int dbase = (tid >> 5) * 32;
        const float* xp = in + (size_t)b * BSTRIDE + hw0 + px;
#pragma unroll 8
        for (int dd = 0; dd < 32; ++dd) {
            const int d = dbase + dd;
            float v = xp[(size_t)d * 1024];
            unsigned short hb = bf16_rne(v);
            float l = v - bf16_to_f(hb);
            xh[px][d] = hb;
            xl[px][d] = bf16_rne(l);
        }
    }

    // sx for this lane's 8 pixel-slots: px = 16*m + quad*4 + r
    float sxv[2][4];
#pragma unroll
    for (int m = 0; m < 2; ++m) {
        float4 t = *(const float4*)(sx_arr + n0 + 16 * m + quad * 4);
        sxv[m][0] = t.x; sxv[m][1] = t.y; sxv[m][2] = t.z; sxv[m][3] = t.w;
    }

    float t1[8], t2[8];
    int   k1[8], k2[8];
#pragma unroll
    for (int i = 0; i < 8; ++i) {
        t1[i] = __uint_as_float(0x7f800000u); t2[i] = t1[i];
        k1[i] = 0; k2[i] = 0;
    }

    __syncthreads();   // x-stage written + slice-0 DMA landed

    f32x4 acc[2][2];
    int buf = 0;
    for (int idx = 0; idx < 64; ++idx) {
        const int cc = idx >> 3;
        const int ds = idx & 7;
        if (ds == 0) {
#pragma unroll
            for (int m = 0; m < 2; ++m)
#pragma unroll
                for (int ns = 0; ns < 2; ++ns)
                    acc[m][ns] = (f32x4){0.f, 0.f, 0.f, 0.f};
        }
        if (idx + 1 < 64) issue_es(idx + 1, buf ^ 1);   // DMA overlaps MFMA below

        s16x8 a_h[2], a_l[2];
#pragma unroll
        for (int m = 0; m < 2; ++m) {
            a_h[m] = *(const s16x8*)&xh[16 * m + l15][ds * 32 + quad * 8];
            a_l[m] = *(const s16x8*)&xl[16 * m + l15][ds * 32 + quad * 8];
        }
#pragma unroll
        for (int ns = 0; ns < 2; ++ns) {
            const int cl = w * 32 + ns * 16 + l15;     // wave owns 32 codes/chunk
            s16x8 bh = *(const s16x8*)&es[buf][0][quad][cl][0];
            s16x8 bl = *(const s16x8*)&es[buf][1][quad][cl][0];
#pragma unroll
            for (int m = 0; m < 2; ++m) {
                acc[m][ns] = __builtin_amdgcn_mfma_f32_16x16x32_bf16(a_h[m], bh, acc[m][ns], 0, 0, 0);
                acc[m][ns] = __builtin_amdgcn_mfma_f32_16x16x32_bf16(a_h[m], bl, acc[m][ns], 0, 0, 0);
                acc[m][ns] = __builtin_amdgcn_mfma_f32_16x16x32_bf16(a_l[m], bh, acc[m][ns], 0, 0, 0);
            }
        }
        if (ds == 7) {
            // fold chunk cc into per-lane top-2 (k ascending: cc asc, ns asc)
            const int kcf = cc << 7;
#pragma unroll
            for (int ns = 0; ns < 2; ++ns) {
                const int c = kcf + w * 32 + ns * 16 + l15;
                const float se = se_arr[c];
#pragma unroll
                for (int m = 0; m < 2; ++m) {
#pragma unroll
                    for (int r = 0; r < 4; ++r) {
                        const int i = m * 4 + r;
                        float dv = __fadd_rn(__fmaf_rn(-2.0f, acc[m][ns][r], sxv[m][r]), se);
                        if (dv < t1[i]) { t2[i] = t1[i]; k2[i] = k1[i]; t1[i] = dv; k1[i] = c; }
                        else if (dv < t2[i]) { t2[i] = dv; k2[i] = c; }
                    }
                }
            }
        }
        __syncthreads();   // drains next-slice DMA + this-slice LDS reads
        buf ^= 1;
    }

    // width-16 butterfly merge of top-2 across the code dimension (l15)
#pragma unroll
    for (int mm = 1; mm < 16; mm <<= 1) {
#pragma unroll
        for (int i = 0; i < 8; ++i) {
            float ov1 = __shfl_xor(t1[i], mm, 16); int ok1 = __shfl_xor(k1[i], mm, 16);
            float ov2 = __shfl_xor(t2[i], mm, 16); int ok2 = __shfl_xor(k2[i], mm, 16);
            if (ov1 < t1[i] || (ov1 == t1[i] && ok1 < k1[i])) {
                t2[i] = t1[i]; k2[i] = k1[i]; t1[i] = ov1; k1[i] = ok1;
            } else if (ov1 < t2[i] || (ov1 == t2[i] && ok1 < k2[i])) {
                t2[i] = ov1; k2[i] = ok1;
            }
            if (ov2 < t2[i] || (ov2 == t2[i] && ok2 < k2[i])) {
                if (ov2 < t1[i] || (ov2 == t1[i] && ok2 < k1[i])) {
                    t2[i] = t1[i]; k2[i] = k1[i]; t1[i] = ov2; k1[i] = ok2;
                } else { t2[i] = ov2; k2[i] = ok2; }
            }
        }
    }
    // lane leaders publish per-wave top-2 per pixel
    if (l15 == 0) {
#pragma unroll
        for (int i = 0; i < 8; ++i) {
            const int px = 16 * (i >> 2) + quad * 4 + (i & 3);
            red[w][px][0] = t1[i];
            red[w][px][1] = __int_as_float(k1[i]);
            red[w][px][2] = t2[i];
            red[w][px][3] = __int_as_float(k2[i]);
        }
    }
    __syncthreads();
    if (tid < 32) {
        const int px = tid;
        float D1 = __uint_as_float(0x7f800000u), D2 = D1;
        int   K1 = 0, K2 = 0;
#pragma unroll
        for (int wv = 0; wv < 4; ++wv) {
            float a1 = red[wv][px][0]; int b1 = __float_as_int(red[wv][px][1]);
            float a2 = red[wv][px][2]; int b2 = __float_as_int(red[wv][px][3]);
            if (a1 < D1 || (a1 == D1 && b1 < K1)) { D2 = D1; K2 = K1; D1 = a1; K1 = b1; }
            else if (a1 < D2 || (a1 == D2 && b1 < K2)) { D2 = a1; K2 = b1; }
            if (a2 < D2 || (a2 == D2 && b2 < K2)) {
                if (a2 < D1 || (a2 == D1 && b2 < K1)) { D2 = D1; K2 = K1; D1 = a2; K1 = b2; }
                else { D2 = a2; K2 = b2; }
            }
        }
        ws64[n0 + px] = ((unsigned long long)f2key(D1) << 32) | (unsigned)K1;
        if (__fsub_rn(D2, D1) <= THRESH) {
            int qi = atomicAdd(qcount, 1);
            qlist[qi] = n0 + px;
        }
    }
}

// ---------------------------------------------------------------------------
// Kernel 2b: exact slow path, COALESCED via embT[d][k] (proven round 7).
// ---------------------------------------------------------------------------
__global__ __launch_bounds__(256, 4)
void vq_slow(const float* __restrict__ in, const float* __restrict__ embT,
             const float* __restrict__ sx_arr, const float* __restrict__ se_arr,
             const int* __restrict__ qcount, const int* __restrict__ qlist,
             unsigned long long* __restrict__ ws64) {
    __shared__ float xs[4][256];
    const int nq = *qcount;
    const int t = threadIdx.x;
    const int w = t >> 6;    // pixel slot 0..3 (one wave per pixel)
    const int l = t & 63;

    for (int base = blockIdx.x * 4; base < nq; base += 1024 * 4) {
        const int qi = base + w;
        const bool valid = (qi < nq);
        const int n = qlist[valid ? qi : base];
        __syncthreads();   // previous-iteration readers done
        {
            const float* src = in + (size_t)(n >> 10) * BSTRIDE + (n & 1023);
#pragma unroll
            for (int i = 0; i < 4; ++i)
                xs[w][l + 64 * i] = src[(size_t)(l + 64 * i) * 1024];
        }
        __syncthreads();

        const float sx = sx_arr[n];
        float m[16];
#pragma unroll
        for (int j = 0; j < 16; ++j) m[j] = 0.0f;

#pragma unroll 2
        for (int d = 0; d < 256; ++d) {
            const float xv = xs[w][d];
            const float* row = embT + (size_t)d * KCODE + 4 * l;
#pragma unroll
            for (int g = 0; g < 4; ++g) {
                float4 ev = *(const float4*)(row + 256 * g);
                m[4 * g + 0] = __fmaf_rn(xv, ev.x, m[4 * g + 0]);
                m[4 * g + 1] = __fmaf_rn(xv, ev.y, m[4 * g + 1]);
                m[4 * g + 2] = __fmaf_rn(xv, ev.z, m[4 * g + 2]);
                m[4 * g + 3] = __fmaf_rn(xv, ev.w, m[4 * g + 3]);
            }
        }
        float bestv = __uint_as_float(0x7f800000u);
        int   bestk = 0;
#pragma unroll
        for (int g = 0; g < 4; ++g) {
#pragma unroll
            for (int c = 0; c < 4; ++c) {
                const int k = 4 * l + c + 256 * g;
                float dv = __fadd_rn(__fmaf_rn(-2.0f, m[4 * g + c], sx), se_arr[k]);
                if (dv < bestv) { bestv = dv; bestk = k; }   // k ascending, strict <
            }
        }
        // full-wave merge (64 lanes, one pixel per wave), tie -> smaller k
#pragma unroll
        for (int mm = 1; mm < 64; mm <<= 1) {
            float ov = __shfl_xor(bestv, mm, 64);
            int   ok = __shfl_xor(bestk, mm, 64);
            if (ov < bestv || (ov == bestv && ok < bestk)) { bestv = ov; bestk = ok; }
        }
        if (l == 0 && valid)
            ws64[n] = ((unsigned long long)f2key(bestv) << 32) | (unsigned)bestk;
    }
}

// ---------------------------------------------------------------------------
// Kernel 3: gather quantized rows, straight-through output + indices + loss.
// (unchanged, proven)
// ---------------------------------------------------------------------------
__global__ void vq_write(const float* __restrict__ in, const float* __restrict__ emb,
                         const unsigned long long* __restrict__ ws64,
                         float* __restrict__ out0, float* __restrict__ out2,
                         float* __restrict__ loss_acc) {
    const int nt = blockIdx.x;
    const int n0 = nt << 7;
    const int b  = n0 >> 10;
    const int hw0 = n0 & 1023;
    const int tid = threadIdx.x;
    const int n_l = tid & 127;
    const int ch0 = tid >> 7;

    const int k = (int)(unsigned int)(ws64[n0 + n_l] & 0xFFFFFFFFull);
    if (tid < 128) out2[n0 + tid] = (float)k;

    const float* xrow = in  + (size_t)b * BSTRIDE + hw0 + n_l;
    float*       orow = out0 + (size_t)b * BSTRIDE + hw0 + n_l;
    const float* erow = emb + (size_t)k * DIM;

    float lsum = 0.0f;
    for (int it = 0; it < 128; ++it) {
        const int ch = it * 2 + ch0;
        float x = xrow[(size_t)ch * 1024];
        float q = erow[ch];
        float df = __fsub_rn(q, x);
        orow[(size_t)ch * 1024] = __fadd_rn(x, df);
        lsum = __fadd_rn(lsum, __fmul_rn(df, df));
    }
#pragma unroll
    for (int off = 32; off >= 1; off >>= 1)
        lsum += __shfl_down(lsum, off, 64);
    __shared__ float wsum[4];
    if ((tid & 63) == 0) wsum[tid >> 6] = lsum;
    __syncthreads();
    if (tid == 0) {
        float tt = wsum[0] + wsum[1] + wsum[2] + wsum[3];
        atomicAdd(loss_acc, tt);
    }
}

// ---------------------------------------------------------------------------
// Kernel 4: finalize loss (unchanged).
// ---------------------------------------------------------------------------
__global__ void vq_loss(const float* __restrict__ loss_acc, float* __restrict__ out1) {
    float s = *loss_acc;
    float e = s * (1.0f / 8388608.0f);
    out1[0] = __fadd_rn(e, __fmul_rn(0.25f, e));
}

extern "C" void kernel_launch(void* const* d_in, const int* in_sizes, int n_in,
                              void* d_out, int out_size, void* d_ws, size_t ws_size,
                              hipStream_t stream) {
    const float* in  = (const float*)d_in[0];
    const float* emb = (const float*)d_in[1];
    float* out = (float*)d_out;

    // d_ws: proven layout
    unsigned long long* ws64 = (unsigned long long*)d_ws;          // 32768 * 8 B
    float* wsf     = (float*)((char*)d_ws + NPIX * sizeof(unsigned long long));
    float* lossacc = wsf;
    float* sx_arr  = wsf + 256;
    float* se_arr  = wsf + 256 + NPIX;

    // Scratch in d_out's quantized region (vq_write overwrites it all, last):
    // [0, 1 MB): ebf hi/lo planes; [1 MB, ~1.13 MB): qcount + qlist;
    // [2 MB, 3 MB): embT (fp32 transposed codebook).
    unsigned short* ebf_h = (unsigned short*)d_out;                // 262144 u16
    unsigned short* ebf_l = ebf_h + KCODE * DIM;                   // 262144 u16
    int* qcount = (int*)((char*)d_out + 2u * KCODE * DIM * sizeof(unsigned short));
    int* qlist  = qcount + 1;                                      // up to 32768 ints
    float* embT = (float*)((char*)d_out + (2u << 20));             // 262144 f32

    vq_sums<<<(NPIX + KCODE) / 64, 256, 0, stream>>>(in, emb, sx_arr, se_arr, lossacc);
    vq_prep<<<256, 256, 0, stream>>>(emb, ebf_h, ebf_l, embT, qcount);
    vq_mfma<<<1024, 256, 0, stream>>>(in, ebf_h, ebf_l, sx_arr, se_arr, ws64, qcount, qlist);
    vq_slow<<<1024, 256, 0, stream>>>(in, embT, sx_arr, se_arr, qcount, qlist, ws64);
    vq_write<<<256, 256, 0, stream>>>(in, emb, ws64, out, out + OUT0_N + 1, lossacc);
    vq_loss<<<1, 1, 0, stream>>>(lossacc, out + OUT0_N);
}